// Round 10
// baseline (236.950 us; speedup 1.0000x reference)
//
#include <hip/hip_runtime.h>
#include <math.h>

#define RES 128
#define RES2 (RES*RES)
#define RES3 (RES*RES*RES)
#define NROWS 16384   // 128*128 (x,y) row bins

__device__ __forceinline__ int brev7(unsigned x){ return (int)(__brev(x) >> 25); }
// storage index (bit-rev order after DIF) -> signed integer frequency
__device__ __forceinline__ float freq_of(int s){ int k = brev7((unsigned)s); return (float)(k < 64 ? k : k - 128); }
__device__ __forceinline__ float2 cmul(float2 a, float2 b){
    return make_float2(a.x*b.x - a.y*b.y, a.x*b.y + a.y*b.x);
}
__device__ __forceinline__ float2 twd(float ang){ float s, c; __sincosf(ang, &s, &c); return make_float2(c, s); }

// Lane-dependent twiddles for the 128-pt wave FFT (7 sincos, computed once per thread).
struct TW { float2 s64; float2 w[6]; };
__device__ __forceinline__ TW make_tw(int tt){
    TW t;
    t.s64 = twd(-(float)M_PI * (float)tt * (1.f/64.f));
    #pragma unroll
    for (int i = 0; i < 6; i++){
        int h = 32 >> i;
        t.w[i] = twd(-(float)M_PI * (float)(tt & (h - 1)) / (float)h);
    }
    return t;
}

// Forward DIF radix-2, 128 points across one wave: lane tt holds x[tt] (r0), x[tt+64] (r1).
// Natural input -> bit-reversed-order spectrum.
__device__ __forceinline__ void dif128_t(float2& r0, float2& r1, int tt, const TW& tw){
    {   // h = 64 stage, in-lane pair (tt, tt+64)
        float2 a = r0, b = r1;
        r0 = make_float2(a.x + b.x, a.y + b.y);
        float2 d = make_float2(a.x - b.x, a.y - b.y);
        r1 = cmul(d, tw.s64);
    }
    #pragma unroll
    for (int i = 0; i < 6; i++){
        int h = 32 >> i;
        int bit = tt & h;
        float2 w = tw.w[i];
        float2 o0 = make_float2(__shfl_xor(r0.x, h), __shfl_xor(r0.y, h));
        float2 o1 = make_float2(__shfl_xor(r1.x, h), __shfl_xor(r1.y, h));
        if (!bit){
            r0.x += o0.x; r0.y += o0.y;
            r1.x += o1.x; r1.y += o1.y;
        } else {
            r0 = cmul(make_float2(o0.x - r0.x, o0.y - r0.y), w);
            r1 = cmul(make_float2(o1.x - r1.x, o1.y - r1.y), w);
        }
    }
}

// Inverse DIT radix-2: bit-reversed-order input -> natural output (unscaled).
__device__ __forceinline__ void dit128_t(float2& r0, float2& r1, int tt, const TW& tw){
    #pragma unroll
    for (int i = 5; i >= 0; i--){
        int h = 32 >> i;           // 1,2,4,8,16,32
        int bit = tt & h;
        float2 w = make_float2(tw.w[i].x, -tw.w[i].y);   // conjugate
        float2 o0 = make_float2(__shfl_xor(r0.x, h), __shfl_xor(r0.y, h));
        float2 o1 = make_float2(__shfl_xor(r1.x, h), __shfl_xor(r1.y, h));
        if (!bit){
            float2 t0 = cmul(o0, w), t1 = cmul(o1, w);
            r0.x += t0.x; r0.y += t0.y;
            r1.x += t1.x; r1.y += t1.y;
        } else {
            float2 t0 = cmul(r0, w), t1 = cmul(r1, w);
            r0 = make_float2(o0.x - t0.x, o0.y - t0.y);
            r1 = make_float2(o1.x - t1.x, o1.y - t1.y);
        }
    }
    {   // h = 64 stage, in-lane
        float2 w = make_float2(tw.s64.x, -tw.s64.y);
        float2 b = cmul(r1, w);
        float2 a = r0;
        r0 = make_float2(a.x + b.x, a.y + b.y);
        r1 = make_float2(a.x - b.x, a.y - b.y);
    }
}

// ---- point binning: histogram over (lx,ly) rows ----
__global__ void hist_kernel(const float* __restrict__ pts, int* __restrict__ counts, int N){
    int i = blockIdx.x * blockDim.x + threadIdx.x;
    if (i >= N) return;
    float prx = pts[3*i] * RES, pry = pts[3*i+1] * RES;
    int lx = ((int)floorf(prx)) & 127, ly = ((int)floorf(pry)) & 127;
    atomicAdd(&counts[(lx << 7) | ly], 1);
}

// single-block exclusive scan over 16384 counts; starts[NROWS] = total; also fills cursors
__global__ __launch_bounds__(1024) void rowscan(const int* __restrict__ counts,
                                                int* __restrict__ starts,
                                                int* __restrict__ cursors){
    __shared__ int buf[2][1024];
    int t = threadIdx.x;
    int c[16];
    int base = t * 16;
    int s = 0;
    #pragma unroll
    for (int k = 0; k < 16; k++){ c[k] = counts[base + k]; s += c[k]; }
    buf[0][t] = s;
    __syncthreads();
    int cur = 0;
    for (int d = 1; d < 1024; d <<= 1){
        int v = buf[cur][t];
        if (t >= d) v += buf[cur][t - d];
        buf[cur ^ 1][t] = v;
        cur ^= 1;
        __syncthreads();
    }
    int incl = buf[cur][t];
    int run = incl - s;   // exclusive
    #pragma unroll
    for (int k = 0; k < 16; k++){ starts[base + k] = run; cursors[base + k] = run; run += c[k]; }
    if (t == 1023) starts[NROWS] = incl;
}

// place points into row-sorted order (AoS stride 6: px,py,pz,n0,n1,n2)
__global__ void scatter_sorted(const float* __restrict__ pts, const float* __restrict__ nrm,
                               int* __restrict__ cursors, float* __restrict__ sorted, int N){
    int i = blockIdx.x * blockDim.x + threadIdx.x;
    if (i >= N) return;
    float px = pts[3*i], py = pts[3*i+1], pz = pts[3*i+2];
    int lx = ((int)floorf(px * RES)) & 127, ly = ((int)floorf(py * RES)) & 127;
    int pos = atomicAdd(&cursors[(lx << 7) | ly], 1);
    float* q = sorted + (size_t)pos * 6;
    q[0] = px; q[1] = py; q[2] = pz;
    q[3] = nrm[3*i]; q[4] = nrm[3*i+1]; q[5] = nrm[3*i+2];
}

// ---- rasterize a 4-column y-strip (x, y0..y0+3) via LDS atomics, then z-FFT all
// 3 channels x 4 columns with 12 waves (768 threads). Writes complex z-spectra.
__global__ __launch_bounds__(768) void gather_z(const float* __restrict__ sorted,
                                                const int* __restrict__ starts,
                                                float2* __restrict__ zF){
    __shared__ float col[3][4][RES];   // 6 KB
    int x  = blockIdx.x >> 5;          // 0..127
    int y0 = (blockIdx.x & 31) << 2;   // 0,4,...,124
    int t = threadIdx.x;
    ((float*)col)[t] = 0.f;
    ((float*)col)[t + 768] = 0.f;
    __syncthreads();
    int xm = (x + 127) & 127;
    // contiguous row-ranges: rows (xi, y0-1 .. y0+3); split in two at the y-wrap
    int ybase = (y0 == 0) ? 127 : (y0 - 1);
    int n1 = (y0 == 0) ? 1 : 5;
    int n2 = 5 - n1;
    int a_s[4], a_e[4];
    { int r = (xm << 7) | ybase; a_s[0] = starts[r]; a_e[0] = starts[r + n1]; }
    { int r = (xm << 7);         a_s[1] = starts[r]; a_e[1] = starts[r + n2]; }
    { int r = (x  << 7) | ybase; a_s[2] = starts[r]; a_e[2] = starts[r + n1]; }
    { int r = (x  << 7);         a_s[3] = starts[r]; a_e[3] = starts[r + n2]; }
    int p1 = a_e[0] - a_s[0];
    int p2 = p1 + (a_e[1] - a_s[1]);
    int p3 = p2 + (a_e[2] - a_s[2]);
    int tot = p3 + (a_e[3] - a_s[3]);
    for (int base = 0; base < tot; base += 768){
        int k = base + t;
        if (k < tot){
            int i;
            if      (k < p1) i = a_s[0] + k;
            else if (k < p2) i = a_s[1] + (k - p1);
            else if (k < p3) i = a_s[2] + (k - p2);
            else             i = a_s[3] + (k - p3);
            const float* q = sorted + (size_t)i * 6;
            float prx = q[0]*RES, pry = q[1]*RES, prz = q[2]*RES;
            float flx = floorf(prx), fly = floorf(pry), flz = floorf(prz);
            float fx = prx - flx, fy = pry - fly, fz = prz - flz;
            int lxp = ((int)flx) & 127, lyp = ((int)fly) & 127, lz = ((int)flz) & 127;
            float wx = (lxp == x) ? (1.f - fx) : fx;
            int z1 = (lz + 1) & 127;
            float n0 = q[3], nv1 = q[4], nv2 = q[5];
            int jA = (lyp - y0) & 127;          // column getting (1-fy)
            int jB = (jA + 1) & 127;            // column getting fy
            if (jA < 4){
                float wy = wx * (1.f - fy);
                float w0 = wy * (1.f - fz), w1 = wy * fz;
                atomicAdd(&col[0][jA][lz], w0*n0);  atomicAdd(&col[0][jA][z1], w1*n0);
                atomicAdd(&col[1][jA][lz], w0*nv1); atomicAdd(&col[1][jA][z1], w1*nv1);
                atomicAdd(&col[2][jA][lz], w0*nv2); atomicAdd(&col[2][jA][z1], w1*nv2);
            }
            if (jB < 4){
                float wy = wx * fy;
                float w0 = wy * (1.f - fz), w1 = wy * fz;
                atomicAdd(&col[0][jB][lz], w0*n0);  atomicAdd(&col[0][jB][z1], w1*n0);
                atomicAdd(&col[1][jB][lz], w0*nv1); atomicAdd(&col[1][jB][z1], w1*nv1);
                atomicAdd(&col[2][jB][lz], w0*nv2); atomicAdd(&col[2][jB][z1], w1*nv2);
            }
        }
    }
    __syncthreads();
    int w = t >> 6, tt = t & 63;     // 12 waves: wave w -> channel w>>2, column w&3
    int c = w >> 2, j = w & 3;
    TW tw = make_tw(tt);
    float2 r0 = make_float2(col[c][j][tt], 0.f);
    float2 r1 = make_float2(col[c][j][tt + 64], 0.f);
    dif128_t(r0, r1, tt, tw);
    float2* qo = zF + (size_t)c * RES3 + (((size_t)x << 14) | ((size_t)(y0 + j) << 7));
    qo[tt] = r0; qo[tt + 64] = r1;
}

// ---- all-channel y pass: bufA = f_y*Y(V1) + f_z*Y(V2); bufB = Y(V0) ----
__global__ __launch_bounds__(1024) void mega_y(const float2* __restrict__ zF,
                                               float2* __restrict__ bufA,
                                               float2* __restrict__ bufB){
    __shared__ float2 tile[16][130];
    int t = threadIdx.x;
    int x = blockIdx.x >> 3, z0 = (blockIdx.x & 7) << 4;
    size_t base = ((size_t)x << 14) + (size_t)z0;
    int y0 = t >> 4, zz = t & 15, y1 = y0 + 64;
    size_t i0 = base + ((size_t)y0 << 7) + zz;
    size_t i1 = base + ((size_t)y1 << 7) + zz;
    int w = t >> 6, tt = t & 63;
    TW tw = make_tw(tt);
    // c1: * f_y
    tile[zz][y0] = zF[RES3 + i0]; tile[zz][y1] = zF[RES3 + i1];
    __syncthreads();
    float2 A0 = tile[w][tt], A1 = tile[w][tt + 64];
    __syncthreads();
    dif128_t(A0, A1, tt, tw);
    { float f0 = freq_of(tt), f1 = freq_of(tt + 64);
      A0.x *= f0; A0.y *= f0; A1.x *= f1; A1.y *= f1; }
    // c2: * f_z, accumulate
    tile[zz][y0] = zF[2*(size_t)RES3 + i0]; tile[zz][y1] = zF[2*(size_t)RES3 + i1];
    __syncthreads();
    float2 C0 = tile[w][tt], C1 = tile[w][tt + 64];
    __syncthreads();
    dif128_t(C0, C1, tt, tw);
    { float fz = freq_of(z0 + w);
      A0.x += fz*C0.x; A0.y += fz*C0.y; A1.x += fz*C1.x; A1.y += fz*C1.y; }
    // c0: plain
    tile[zz][y0] = zF[i0]; tile[zz][y1] = zF[i1];
    __syncthreads();
    float2 B0 = tile[w][tt], B1 = tile[w][tt + 64];
    __syncthreads();
    dif128_t(B0, B1, tt, tw);
    // write A
    tile[w][tt] = A0; tile[w][tt + 64] = A1;
    __syncthreads();
    bufA[i0] = tile[zz][y0]; bufA[i1] = tile[zz][y1];
    __syncthreads();
    // write B
    tile[w][tt] = B0; tile[w][tt + 64] = B1;
    __syncthreads();
    bufB[i0] = tile[zz][y0]; bufB[i1] = tile[zz][y1];
}

// ---- x mega-pass: fwd-x both buffers, combine f_x*B + A, spectral scale, inverse-x, write bufA ----
__global__ __launch_bounds__(1024) void x_mega(const float2* __restrict__ bufB,  // V0, y-passed
                                               float2* __restrict__ bufA){       // f_y*V1 + f_z*V2, y-passed
    __shared__ float2 tA[16][130];
    __shared__ float2 tB[16][130];
    int t = threadIdx.x;
    int y = blockIdx.x >> 3, z0 = (blockIdx.x & 7) << 4;
    size_t base = ((size_t)y << 7) + (size_t)z0;
    int x0 = t >> 4, zz = t & 15;
    int x1 = x0 + 64;
    size_t g0 = base + ((size_t)x0 << 14) + zz;
    size_t g1 = base + ((size_t)x1 << 14) + zz;
    tA[zz][x0] = bufA[g0]; tA[zz][x1] = bufA[g1];
    tB[zz][x0] = bufB[g0]; tB[zz][x1] = bufB[g1];
    __syncthreads();
    int w = t >> 6, tt = t & 63;
    TW tw = make_tw(tt);
    float2 a0 = tA[w][tt], a1 = tA[w][tt + 64];
    float2 b0 = tB[w][tt], b1 = tB[w][tt + 64];
    dif128_t(a0, a1, tt, tw);
    dif128_t(b0, b1, tt, tw);
    float fy = freq_of(y), fz = freq_of(z0 + w);
    float fyz = fy*fy + fz*fz;
    const float K = -2.f * (2.f/128.f) * (2.f/128.f);   // -2*(SIGMA/RES)^2
    {
        float fx = freq_of(tt);
        float vx = a0.x + fx*b0.x, vy = a0.y + fx*b0.y;
        float usq = fx*fx + fyz;
        float s = __expf(K*usq) / ((usq + 1e-6f) * (2.f*(float)M_PI));
        a0 = make_float2(s*vy, -s*vx);
    }
    {
        float fx = freq_of(tt + 64);
        float vx = a1.x + fx*b1.x, vy = a1.y + fx*b1.y;
        float usq = fx*fx + fyz;
        float s = __expf(K*usq) / ((usq + 1e-6f) * (2.f*(float)M_PI));
        a1 = make_float2(s*vy, -s*vx);
    }
    dit128_t(a0, a1, tt, tw);
    tA[w][tt] = a0; tA[w][tt + 64] = a1;
    __syncthreads();
    bufA[g0] = tA[zz][x0];
    bufA[g1] = tA[zz][x1];
}

// ---- inverse y pass (plain) ----
__global__ __launch_bounds__(1024) void inv_y(float2* __restrict__ data){
    __shared__ float2 tile[16][130];
    int t = threadIdx.x;
    int x = blockIdx.x >> 3, z0 = (blockIdx.x & 7) << 4;
    size_t base = ((size_t)x << 14) + (size_t)z0;
    int y0 = t >> 4, zz = t & 15, y1 = y0 + 64;
    size_t i0 = base + ((size_t)y0 << 7) + zz;
    size_t i1 = base + ((size_t)y1 << 7) + zz;
    tile[zz][y0] = data[i0]; tile[zz][y1] = data[i1];
    __syncthreads();
    int w = t >> 6, tt = t & 63;
    TW tw = make_tw(tt);
    float2 r0 = tile[w][tt], r1 = tile[w][tt + 64];
    dit128_t(r0, r1, tt, tw);
    tile[w][tt] = r0; tile[w][tt + 64] = r1;
    __syncthreads();
    data[i0] = tile[zz][y0]; data[i1] = tile[zz][y1];
}

__global__ __launch_bounds__(256) void inv_z_c2r(const float2* __restrict__ in, float* __restrict__ out){
    int t = threadIdx.x; int wid = t >> 6, tt = t & 63;
    size_t line = (size_t)blockIdx.x * 4 + wid;
    const float2* p = in + line * RES;
    TW tw = make_tw(tt);
    float2 r0 = p[tt], r1 = p[tt + 64];
    dit128_t(r0, r1, tt, tw);
    const float sc = 1.f / (float)RES3;
    float* q = out + line * RES;
    q[tt] = r0.x * sc; q[tt + 64] = r1.x * sc;
}

__global__ void interp_sum(const float* __restrict__ chi, const float* __restrict__ pts,
                           float* __restrict__ sum, int N){
    int i = blockIdx.x * blockDim.x + threadIdx.x;
    float val = 0.f;
    if (i < N){
        float px = pts[3*i], py = pts[3*i+1], pz = pts[3*i+2];
        float prx = px * RES, pry = py * RES, prz = pz * RES;
        float lox = floorf(prx), loy = floorf(pry), loz = floorf(prz);
        int lix = ((int)lox) & 127, liy = ((int)loy) & 127, liz = ((int)loz) & 127;
        int uix = ((int)ceilf(prx)) & 127, uiy = ((int)ceilf(pry)) & 127, uiz = ((int)ceilf(prz)) & 127;
        float fx = prx - lox, fy = pry - loy, fz = prz - loz;
        #pragma unroll
        for (int cx = 0; cx < 2; cx++){
            int ix = cx ? uix : lix;
            float wx = cx ? fx : 1.f - fx;
            #pragma unroll
            for (int cy = 0; cy < 2; cy++){
                int iy = cy ? uiy : liy;
                float wxy = wx * (cy ? fy : 1.f - fy);
                #pragma unroll
                for (int cz = 0; cz < 2; cz++){
                    int iz = cz ? uiz : liz;
                    float w = wxy * (cz ? fz : 1.f - fz);
                    val += w * chi[(ix << 14) + (iy << 7) + iz];
                }
            }
        }
    }
    __shared__ float red[256];
    int tid = threadIdx.x;
    red[tid] = val;
    __syncthreads();
    #pragma unroll
    for (int s2 = 128; s2 > 0; s2 >>= 1){
        if (tid < s2) red[tid] += red[tid + s2];
        __syncthreads();
    }
    if (tid == 0) atomicAdd(sum, red[0]);
}

__global__ void final_scale(const float* __restrict__ chi, const float* __restrict__ sum,
                            float* __restrict__ out, float invN){
    int i = blockIdx.x * blockDim.x + threadIdx.x;
    if (i >= RES3) return;
    float mean = sum[0] * invN;
    float sc = 0.5f / fabsf(chi[0] - mean);
    out[i] = sc * (chi[i] - mean);
}

extern "C" void kernel_launch(void* const* d_in, const int* in_sizes, int n_in,
                              void* d_out, int out_size, void* d_ws, size_t ws_size,
                              hipStream_t stream) {
    const float* points  = (const float*)d_in[0];
    const float* normals = (const float*)d_in[1];
    float* out = (float*)d_out;
    char* ws = (char*)d_ws;

    size_t off = 0;
    float2* zF     = (float2*)(ws + off); off += (size_t)3*RES3*8;   // 48 MB
    float2* bufA   = (float2*)(ws + off); off += (size_t)RES3*8;     // 16 MB
    float2* bufB   = (float2*)(ws + off); off += (size_t)RES3*8;     // 16 MB
    float*  chiP   = (float*) (ws + off); off += (size_t)RES3*4;     //  8 MB
    float*  sumb   = (float*) (ws + off); off += 64;
    int*    counts = (int*)   (ws + off); off += (size_t)NROWS*4;
    int*    starts = (int*)   (ws + off); off += (size_t)(NROWS+1)*4;
    int*    cursors= (int*)   (ws + off); off += (size_t)NROWS*4;
    float*  sorted = (float*) (ws + off);                            // N*6 floats

    int N = in_sizes[0] / 3;

    hipMemsetAsync(counts, 0, (size_t)NROWS*4, stream);
    hipMemsetAsync(sumb, 0, 16, stream);

    hist_kernel<<<(N + 255)/256, 256, 0, stream>>>(points, counts, N);
    rowscan<<<1, 1024, 0, stream>>>(counts, starts, cursors);
    scatter_sorted<<<(N + 255)/256, 256, 0, stream>>>(points, normals, cursors, sorted, N);
    gather_z<<<128*32, 768, 0, stream>>>(sorted, starts, zF);

    mega_y<<<1024, 1024, 0, stream>>>(zF, bufA, bufB);
    x_mega<<<1024, 1024, 0, stream>>>(bufB, bufA);
    inv_y<<<1024, 1024, 0, stream>>>(bufA);
    inv_z_c2r<<<RES2/4, 256, 0, stream>>>(bufA, chiP);

    interp_sum<<<(N + 255)/256, 256, 0, stream>>>(chiP, points, sumb, N);
    final_scale<<<RES3/256, 256, 0, stream>>>(chiP, sumb, out, 1.0f / (float)N);
}

// Round 11
// 232.000 us; speedup vs baseline: 1.0213x; 1.0213x over previous
//
#include <hip/hip_runtime.h>
#include <math.h>

#define RES 128
#define RES2 (RES*RES)
#define RES3 (RES*RES*RES)
#define NROWS 16384   // 128*128 (x,y) row bins
#define STRIPW 32     // gather strip width in y

__device__ __forceinline__ int brev7(unsigned x){ return (int)(__brev(x) >> 25); }
__device__ __forceinline__ float freq_of(int s){ int k = brev7((unsigned)s); return (float)(k < 64 ? k : k - 128); }
__device__ __forceinline__ float2 cmul(float2 a, float2 b){
    return make_float2(a.x*b.x - a.y*b.y, a.x*b.y + a.y*b.x);
}
__device__ __forceinline__ float2 twd(float ang){ float s, c; __sincosf(ang, &s, &c); return make_float2(c, s); }

// Lane-dependent twiddles for the 128-pt wave FFT (7 sincos, once per thread).
struct TW { float2 s64; float2 w[6]; };
__device__ __forceinline__ TW make_tw(int tt){
    TW t;
    t.s64 = twd(-(float)M_PI * (float)tt * (1.f/64.f));
    #pragma unroll
    for (int i = 0; i < 6; i++){
        int h = 32 >> i;
        t.w[i] = twd(-(float)M_PI * (float)(tt & (h - 1)) / (float)h);
    }
    return t;
}

// Forward DIF radix-2, natural -> bit-rev storage.
__device__ __forceinline__ void dif128_t(float2& r0, float2& r1, int tt, const TW& tw){
    {
        float2 a = r0, b = r1;
        r0 = make_float2(a.x + b.x, a.y + b.y);
        float2 d = make_float2(a.x - b.x, a.y - b.y);
        r1 = cmul(d, tw.s64);
    }
    #pragma unroll
    for (int i = 0; i < 6; i++){
        int h = 32 >> i;
        int bit = tt & h;
        float2 w = tw.w[i];
        float2 o0 = make_float2(__shfl_xor(r0.x, h), __shfl_xor(r0.y, h));
        float2 o1 = make_float2(__shfl_xor(r1.x, h), __shfl_xor(r1.y, h));
        if (!bit){
            r0.x += o0.x; r0.y += o0.y;
            r1.x += o1.x; r1.y += o1.y;
        } else {
            r0 = cmul(make_float2(o0.x - r0.x, o0.y - r0.y), w);
            r1 = cmul(make_float2(o1.x - r1.x, o1.y - r1.y), w);
        }
    }
}

// Inverse DIT radix-2, bit-rev -> natural (unscaled).
__device__ __forceinline__ void dit128_t(float2& r0, float2& r1, int tt, const TW& tw){
    #pragma unroll
    for (int i = 5; i >= 0; i--){
        int h = 32 >> i;
        int bit = tt & h;
        float2 w = make_float2(tw.w[i].x, -tw.w[i].y);
        float2 o0 = make_float2(__shfl_xor(r0.x, h), __shfl_xor(r0.y, h));
        float2 o1 = make_float2(__shfl_xor(r1.x, h), __shfl_xor(r1.y, h));
        if (!bit){
            float2 t0 = cmul(o0, w), t1 = cmul(o1, w);
            r0.x += t0.x; r0.y += t0.y;
            r1.x += t1.x; r1.y += t1.y;
        } else {
            float2 t0 = cmul(r0, w), t1 = cmul(r1, w);
            r0 = make_float2(o0.x - t0.x, o0.y - t0.y);
            r1 = make_float2(o1.x - t1.x, o1.y - t1.y);
        }
    }
    {
        float2 w = make_float2(tw.s64.x, -tw.s64.y);
        float2 b = cmul(r1, w);
        float2 a = r0;
        r0 = make_float2(a.x + b.x, a.y + b.y);
        r1 = make_float2(a.x - b.x, a.y - b.y);
    }
}

__global__ void hist_kernel(const float* __restrict__ pts, int* __restrict__ counts, int N){
    int i = blockIdx.x * blockDim.x + threadIdx.x;
    if (i >= N) return;
    float prx = pts[3*i] * RES, pry = pts[3*i+1] * RES;
    int lx = ((int)floorf(prx)) & 127, ly = ((int)floorf(pry)) & 127;
    atomicAdd(&counts[(lx << 7) | ly], 1);
}

__global__ __launch_bounds__(1024) void rowscan(const int* __restrict__ counts,
                                                int* __restrict__ starts,
                                                int* __restrict__ cursors){
    __shared__ int buf[2][1024];
    int t = threadIdx.x;
    int c[16];
    int base = t * 16;
    int s = 0;
    #pragma unroll
    for (int k = 0; k < 16; k++){ c[k] = counts[base + k]; s += c[k]; }
    buf[0][t] = s;
    __syncthreads();
    int cur = 0;
    for (int d = 1; d < 1024; d <<= 1){
        int v = buf[cur][t];
        if (t >= d) v += buf[cur][t - d];
        buf[cur ^ 1][t] = v;
        cur ^= 1;
        __syncthreads();
    }
    int incl = buf[cur][t];
    int run = incl - s;
    #pragma unroll
    for (int k = 0; k < 16; k++){ starts[base + k] = run; cursors[base + k] = run; run += c[k]; }
    if (t == 1023) starts[NROWS] = incl;
}

// sorted: stride-8 AoS (px,py,pz,n0)(n1,n2,-,-) -> two aligned float4 per point
__global__ void scatter_sorted(const float* __restrict__ pts, const float* __restrict__ nrm,
                               int* __restrict__ cursors, float4* __restrict__ sorted4, int N){
    int i = blockIdx.x * blockDim.x + threadIdx.x;
    if (i >= N) return;
    float px = pts[3*i], py = pts[3*i+1], pz = pts[3*i+2];
    int lx = ((int)floorf(px * RES)) & 127, ly = ((int)floorf(py * RES)) & 127;
    int pos = atomicAdd(&cursors[(lx << 7) | ly], 1);
    sorted4[2*pos]     = make_float4(px, py, pz, nrm[3*i]);
    sorted4[2*pos + 1] = make_float4(nrm[3*i+1], nrm[3*i+2], 0.f, 0.f);
}

// ---- rasterize a 32-wide y-strip (x, y0..y0+31) via LDS atomics, then z-FFT
// 3 channels x 32 columns with 12 waves (8 FFT rounds each). 512 blocks total.
__global__ __launch_bounds__(768) void gather_z(const float4* __restrict__ sorted4,
                                                const int* __restrict__ starts,
                                                float2* __restrict__ zF){
    __shared__ float col[3][STRIPW][RES];   // 48 KB
    int x  = blockIdx.x >> 2;          // 0..127
    int y0 = (blockIdx.x & 3) << 5;    // 0,32,64,96
    int t = threadIdx.x;
    #pragma unroll
    for (int k = 0; k < 16; k++) ((float*)col)[t + 768*k] = 0.f;
    __syncthreads();
    int xm = (x + 127) & 127;
    // rows needed: ly in {y0-1 .. y0+31} (33 consecutive, split at wrap when y0==0)
    int ybase = (y0 == 0) ? 127 : (y0 - 1);
    int n1 = (y0 == 0) ? 1 : 33;
    int n2 = 33 - n1;
    int a_s[4], a_e[4];
    { int r = (xm << 7) | ybase; a_s[0] = starts[r]; a_e[0] = starts[r + n1]; }
    { int r = (xm << 7);         a_s[1] = starts[r]; a_e[1] = starts[r + n2]; }
    { int r = (x  << 7) | ybase; a_s[2] = starts[r]; a_e[2] = starts[r + n1]; }
    { int r = (x  << 7);         a_s[3] = starts[r]; a_e[3] = starts[r + n2]; }
    int p1 = a_e[0] - a_s[0];
    int p2 = p1 + (a_e[1] - a_s[1]);
    int p3 = p2 + (a_e[2] - a_s[2]);
    int tot = p3 + (a_e[3] - a_s[3]);
    for (int base = 0; base < tot; base += 768){
        int k = base + t;
        if (k < tot){
            int i;
            if      (k < p1) i = a_s[0] + k;
            else if (k < p2) i = a_s[1] + (k - p1);
            else if (k < p3) i = a_s[2] + (k - p2);
            else             i = a_s[3] + (k - p3);
            float4 qa = sorted4[2*i];
            float4 qb = sorted4[2*i + 1];
            float prx = qa.x*RES, pry = qa.y*RES, prz = qa.z*RES;
            float flx = floorf(prx), fly = floorf(pry), flz = floorf(prz);
            float fx = prx - flx, fy = pry - fly, fz = prz - flz;
            int lxp = ((int)flx) & 127, lyp = ((int)fly) & 127, lz = ((int)flz) & 127;
            float wx = (lxp == x) ? (1.f - fx) : fx;
            int z1 = (lz + 1) & 127;
            float n0 = qa.w, nv1 = qb.x, nv2 = qb.y;
            int jA = (lyp - y0) & 127;          // column getting (1-fy)
            int jB = (jA + 1) & 127;            // column getting fy
            if (jA < STRIPW){
                float wy = wx * (1.f - fy);
                float w0 = wy * (1.f - fz), w1 = wy * fz;
                atomicAdd(&col[0][jA][lz], w0*n0);  atomicAdd(&col[0][jA][z1], w1*n0);
                atomicAdd(&col[1][jA][lz], w0*nv1); atomicAdd(&col[1][jA][z1], w1*nv1);
                atomicAdd(&col[2][jA][lz], w0*nv2); atomicAdd(&col[2][jA][z1], w1*nv2);
            }
            if (jB < STRIPW){
                float wy = wx * fy;
                float w0 = wy * (1.f - fz), w1 = wy * fz;
                atomicAdd(&col[0][jB][lz], w0*n0);  atomicAdd(&col[0][jB][z1], w1*n0);
                atomicAdd(&col[1][jB][lz], w0*nv1); atomicAdd(&col[1][jB][z1], w1*nv1);
                atomicAdd(&col[2][jB][lz], w0*nv2); atomicAdd(&col[2][jB][z1], w1*nv2);
            }
        }
    }
    __syncthreads();
    int w = t >> 6, tt = t & 63;
    TW tw = make_tw(tt);
    #pragma unroll
    for (int r = 0; r < 8; r++){
        int idx = r * 12 + w;          // 0..95
        int c = idx >> 5, j = idx & 31;
        float2 r0 = make_float2(col[c][j][tt], 0.f);
        float2 r1 = make_float2(col[c][j][tt + 64], 0.f);
        dif128_t(r0, r1, tt, tw);
        float2* qo = zF + (size_t)c * RES3 + (((size_t)x << 14) | ((size_t)(y0 + j) << 7));
        qo[tt] = r0; qo[tt + 64] = r1;
    }
}

// ---- all-channel y pass: bufA = f_y*Y(V1) + f_z*Y(V2); bufB = Y(V0).
// float4-vectorized transposes; all 3 global loads hoisted.
__global__ __launch_bounds__(1024) void mega_y(const float2* __restrict__ zF,
                                               float2* __restrict__ bufA,
                                               float2* __restrict__ bufB){
    __shared__ float2 tile[16][130];
    int t = threadIdx.x;
    int x = blockIdx.x >> 3, z0 = (blockIdx.x & 7) << 4;
    size_t base = ((size_t)x << 14) + (size_t)z0;
    int yv = t >> 3;             // 0..127
    int z2 = (t & 7) << 1;       // 0,2..14
    size_t gi = base + ((size_t)yv << 7) + z2;   // float2 index, even
    const float4* zF4 = (const float4*)zF;
    float4 L1 = zF4[((size_t)RES3 + gi) >> 1];
    float4 L2 = zF4[(2*(size_t)RES3 + gi) >> 1];
    float4 L0 = zF4[gi >> 1];
    int w = t >> 6, tt = t & 63;
    TW tw = make_tw(tt);
    // c1: * f_y
    tile[z2][yv] = make_float2(L1.x, L1.y); tile[z2+1][yv] = make_float2(L1.z, L1.w);
    __syncthreads();
    float2 A0 = tile[w][tt], A1 = tile[w][tt + 64];
    __syncthreads();
    dif128_t(A0, A1, tt, tw);
    { float f0 = freq_of(tt), f1 = freq_of(tt + 64);
      A0.x *= f0; A0.y *= f0; A1.x *= f1; A1.y *= f1; }
    // c2: * f_z, accumulate
    tile[z2][yv] = make_float2(L2.x, L2.y); tile[z2+1][yv] = make_float2(L2.z, L2.w);
    __syncthreads();
    float2 C0 = tile[w][tt], C1 = tile[w][tt + 64];
    __syncthreads();
    dif128_t(C0, C1, tt, tw);
    { float fz = freq_of(z0 + w);
      A0.x += fz*C0.x; A0.y += fz*C0.y; A1.x += fz*C1.x; A1.y += fz*C1.y; }
    // c0: plain
    tile[z2][yv] = make_float2(L0.x, L0.y); tile[z2+1][yv] = make_float2(L0.z, L0.w);
    __syncthreads();
    float2 B0 = tile[w][tt], B1 = tile[w][tt + 64];
    __syncthreads();
    dif128_t(B0, B1, tt, tw);
    // write A
    tile[w][tt] = A0; tile[w][tt + 64] = A1;
    __syncthreads();
    { float2 a = tile[z2][yv], b = tile[z2+1][yv];
      ((float4*)bufA)[gi >> 1] = make_float4(a.x, a.y, b.x, b.y); }
    __syncthreads();
    // write B
    tile[w][tt] = B0; tile[w][tt + 64] = B1;
    __syncthreads();
    { float2 a = tile[z2][yv], b = tile[z2+1][yv];
      ((float4*)bufB)[gi >> 1] = make_float4(a.x, a.y, b.x, b.y); }
}

// ---- x mega-pass: fwd-x both, combine f_x*B + A, spectral scale, inverse-x ----
__global__ __launch_bounds__(1024) void x_mega(const float2* __restrict__ bufB,
                                               float2* __restrict__ bufA){
    __shared__ float2 tA[16][130];
    __shared__ float2 tB[16][130];
    int t = threadIdx.x;
    int y = blockIdx.x >> 3, z0 = (blockIdx.x & 7) << 4;
    size_t base = ((size_t)y << 7) + (size_t)z0;
    int xv = t >> 3, z2 = (t & 7) << 1;
    size_t gi = base + ((size_t)xv << 14) + z2;   // float2 index, even
    float4 LA = ((const float4*)bufA)[gi >> 1];
    float4 LB = ((const float4*)bufB)[gi >> 1];
    tA[z2][xv] = make_float2(LA.x, LA.y); tA[z2+1][xv] = make_float2(LA.z, LA.w);
    tB[z2][xv] = make_float2(LB.x, LB.y); tB[z2+1][xv] = make_float2(LB.z, LB.w);
    __syncthreads();
    int w = t >> 6, tt = t & 63;
    TW tw = make_tw(tt);
    float2 a0 = tA[w][tt], a1 = tA[w][tt + 64];
    float2 b0 = tB[w][tt], b1 = tB[w][tt + 64];
    dif128_t(a0, a1, tt, tw);
    dif128_t(b0, b1, tt, tw);
    float fy = freq_of(y), fz = freq_of(z0 + w);
    float fyz = fy*fy + fz*fz;
    const float K = -2.f * (2.f/128.f) * (2.f/128.f);   // -2*(SIGMA/RES)^2
    {
        float fx = freq_of(tt);
        float vx = a0.x + fx*b0.x, vy = a0.y + fx*b0.y;
        float usq = fx*fx + fyz;
        float s = __expf(K*usq) / ((usq + 1e-6f) * (2.f*(float)M_PI));
        a0 = make_float2(s*vy, -s*vx);
    }
    {
        float fx = freq_of(tt + 64);
        float vx = a1.x + fx*b1.x, vy = a1.y + fx*b1.y;
        float usq = fx*fx + fyz;
        float s = __expf(K*usq) / ((usq + 1e-6f) * (2.f*(float)M_PI));
        a1 = make_float2(s*vy, -s*vx);
    }
    dit128_t(a0, a1, tt, tw);
    tA[w][tt] = a0; tA[w][tt + 64] = a1;
    __syncthreads();
    { float2 a = tA[z2][xv], b = tA[z2+1][xv];
      ((float4*)bufA)[gi >> 1] = make_float4(a.x, a.y, b.x, b.y); }
}

// ---- inverse y pass ----
__global__ __launch_bounds__(1024) void inv_y(float2* __restrict__ data){
    __shared__ float2 tile[16][130];
    int t = threadIdx.x;
    int x = blockIdx.x >> 3, z0 = (blockIdx.x & 7) << 4;
    size_t base = ((size_t)x << 14) + (size_t)z0;
    int yv = t >> 3, z2 = (t & 7) << 1;
    size_t gi = base + ((size_t)yv << 7) + z2;
    float4 L = ((const float4*)data)[gi >> 1];
    tile[z2][yv] = make_float2(L.x, L.y); tile[z2+1][yv] = make_float2(L.z, L.w);
    __syncthreads();
    int w = t >> 6, tt = t & 63;
    TW tw = make_tw(tt);
    float2 r0 = tile[w][tt], r1 = tile[w][tt + 64];
    dit128_t(r0, r1, tt, tw);
    tile[w][tt] = r0; tile[w][tt + 64] = r1;
    __syncthreads();
    { float2 a = tile[z2][yv], b = tile[z2+1][yv];
      ((float4*)data)[gi >> 1] = make_float4(a.x, a.y, b.x, b.y); }
}

__global__ __launch_bounds__(256) void inv_z_c2r(const float2* __restrict__ in, float* __restrict__ out){
    int t = threadIdx.x; int wid = t >> 6, tt = t & 63;
    size_t line = (size_t)blockIdx.x * 4 + wid;
    const float2* p = in + line * RES;
    TW tw = make_tw(tt);
    float2 r0 = p[tt], r1 = p[tt + 64];
    dit128_t(r0, r1, tt, tw);
    const float sc = 1.f / (float)RES3;
    float* q = out + line * RES;
    q[tt] = r0.x * sc; q[tt + 64] = r1.x * sc;
}

__global__ void interp_sum(const float* __restrict__ chi, const float* __restrict__ pts,
                           float* __restrict__ sum, int N){
    int i = blockIdx.x * blockDim.x + threadIdx.x;
    float val = 0.f;
    if (i < N){
        float px = pts[3*i], py = pts[3*i+1], pz = pts[3*i+2];
        float prx = px * RES, pry = py * RES, prz = pz * RES;
        float lox = floorf(prx), loy = floorf(pry), loz = floorf(prz);
        int lix = ((int)lox) & 127, liy = ((int)loy) & 127, liz = ((int)loz) & 127;
        int uix = ((int)ceilf(prx)) & 127, uiy = ((int)ceilf(pry)) & 127, uiz = ((int)ceilf(prz)) & 127;
        float fx = prx - lox, fy = pry - loy, fz = prz - loz;
        #pragma unroll
        for (int cx = 0; cx < 2; cx++){
            int ix = cx ? uix : lix;
            float wx = cx ? fx : 1.f - fx;
            #pragma unroll
            for (int cy = 0; cy < 2; cy++){
                int iy = cy ? uiy : liy;
                float wxy = wx * (cy ? fy : 1.f - fy);
                #pragma unroll
                for (int cz = 0; cz < 2; cz++){
                    int iz = cz ? uiz : liz;
                    float w = wxy * (cz ? fz : 1.f - fz);
                    val += w * chi[(ix << 14) + (iy << 7) + iz];
                }
            }
        }
    }
    __shared__ float red[256];
    int tid = threadIdx.x;
    red[tid] = val;
    __syncthreads();
    #pragma unroll
    for (int s2 = 128; s2 > 0; s2 >>= 1){
        if (tid < s2) red[tid] += red[tid + s2];
        __syncthreads();
    }
    if (tid == 0) atomicAdd(sum, red[0]);
}

__global__ void final_scale(const float* __restrict__ chi, const float* __restrict__ sum,
                            float* __restrict__ out, float invN){
    int i = blockIdx.x * blockDim.x + threadIdx.x;
    if (i >= RES3) return;
    float mean = sum[0] * invN;
    float sc = 0.5f / fabsf(chi[0] - mean);
    out[i] = sc * (chi[i] - mean);
}

extern "C" void kernel_launch(void* const* d_in, const int* in_sizes, int n_in,
                              void* d_out, int out_size, void* d_ws, size_t ws_size,
                              hipStream_t stream) {
    const float* points  = (const float*)d_in[0];
    const float* normals = (const float*)d_in[1];
    float* out = (float*)d_out;
    char* ws = (char*)d_ws;

    size_t off = 0;
    float2* zF     = (float2*)(ws + off); off += (size_t)3*RES3*8;   // 48 MB
    float2* bufA   = (float2*)(ws + off); off += (size_t)RES3*8;     // 16 MB
    float2* bufB   = (float2*)(ws + off); off += (size_t)RES3*8;     // 16 MB
    float*  chiP   = (float*) (ws + off); off += (size_t)RES3*4;     //  8 MB
    float*  sumb   = (float*) (ws + off); off += 64;
    int*    counts = (int*)   (ws + off); off += (size_t)NROWS*4;
    int*    starts = (int*)   (ws + off); off += (size_t)(NROWS+1)*4;
    int*    cursors= (int*)   (ws + off); off += (size_t)NROWS*4;
    off = (off + 15) & ~(size_t)15;
    float4* sorted4 = (float4*)(ws + off);                           // N*8 floats

    int N = in_sizes[0] / 3;

    hipMemsetAsync(counts, 0, (size_t)NROWS*4, stream);
    hipMemsetAsync(sumb, 0, 16, stream);

    hist_kernel<<<(N + 255)/256, 256, 0, stream>>>(points, counts, N);
    rowscan<<<1, 1024, 0, stream>>>(counts, starts, cursors);
    scatter_sorted<<<(N + 255)/256, 256, 0, stream>>>(points, normals, cursors, sorted4, N);
    gather_z<<<128*4, 768, 0, stream>>>(sorted4, starts, zF);

    mega_y<<<1024, 1024, 0, stream>>>(zF, bufA, bufB);
    x_mega<<<1024, 1024, 0, stream>>>(bufB, bufA);
    inv_y<<<1024, 1024, 0, stream>>>(bufA);
    inv_z_c2r<<<RES2/4, 256, 0, stream>>>(bufA, chiP);

    interp_sum<<<(N + 255)/256, 256, 0, stream>>>(chiP, points, sumb, N);
    final_scale<<<RES3/256, 256, 0, stream>>>(chiP, sumb, out, 1.0f / (float)N);
}

// Round 13
// 213.815 us; speedup vs baseline: 1.1082x; 1.0851x over previous
//
#include <hip/hip_runtime.h>
#include <math.h>

#define RES 128
#define RES2 (RES*RES)
#define RES3 (RES*RES*RES)
#define KZ 64         // retained z-frequencies 0..63 (Hermitian half, Nyquist dropped)
#define NROWS 16384
#define STRIPW 32

__device__ __forceinline__ int brev7(unsigned x){ return (int)(__brev(x) >> 25); }
__device__ __forceinline__ float freq_of(int s){ int k = brev7((unsigned)s); return (float)(k < 64 ? k : k - 128); }
__device__ __forceinline__ float2 cmul(float2 a, float2 b){
    return make_float2(a.x*b.x - a.y*b.y, a.x*b.y + a.y*b.x);
}
__device__ __forceinline__ float2 twd(float ang){ float s, c; __sincosf(ang, &s, &c); return make_float2(c, s); }

struct TW { float2 s64; float2 w[6]; };
__device__ __forceinline__ TW make_tw(int tt){
    TW t;
    t.s64 = twd(-(float)M_PI * (float)tt * (1.f/64.f));
    #pragma unroll
    for (int i = 0; i < 6; i++){
        int h = 32 >> i;
        t.w[i] = twd(-(float)M_PI * (float)(tt & (h - 1)) / (float)h);
    }
    return t;
}

// Forward DIF radix-2, natural -> bit-rev storage.
__device__ __forceinline__ void dif128_t(float2& r0, float2& r1, int tt, const TW& tw){
    {
        float2 a = r0, b = r1;
        r0 = make_float2(a.x + b.x, a.y + b.y);
        float2 d = make_float2(a.x - b.x, a.y - b.y);
        r1 = cmul(d, tw.s64);
    }
    #pragma unroll
    for (int i = 0; i < 6; i++){
        int h = 32 >> i;
        int bit = tt & h;
        float2 w = tw.w[i];
        float2 o0 = make_float2(__shfl_xor(r0.x, h), __shfl_xor(r0.y, h));
        float2 o1 = make_float2(__shfl_xor(r1.x, h), __shfl_xor(r1.y, h));
        if (!bit){
            r0.x += o0.x; r0.y += o0.y;
            r1.x += o1.x; r1.y += o1.y;
        } else {
            r0 = cmul(make_float2(o0.x - r0.x, o0.y - r0.y), w);
            r1 = cmul(make_float2(o1.x - r1.x, o1.y - r1.y), w);
        }
    }
}

// Inverse DIT radix-2, bit-rev -> natural (unscaled).
__device__ __forceinline__ void dit128_t(float2& r0, float2& r1, int tt, const TW& tw){
    #pragma unroll
    for (int i = 5; i >= 0; i--){
        int h = 32 >> i;
        int bit = tt & h;
        float2 w = make_float2(tw.w[i].x, -tw.w[i].y);
        float2 o0 = make_float2(__shfl_xor(r0.x, h), __shfl_xor(r0.y, h));
        float2 o1 = make_float2(__shfl_xor(r1.x, h), __shfl_xor(r1.y, h));
        if (!bit){
            float2 t0 = cmul(o0, w), t1 = cmul(o1, w);
            r0.x += t0.x; r0.y += t0.y;
            r1.x += t1.x; r1.y += t1.y;
        } else {
            float2 t0 = cmul(r0, w), t1 = cmul(r1, w);
            r0 = make_float2(o0.x - t0.x, o0.y - t0.y);
            r1 = make_float2(o1.x - t1.x, o1.y - t1.y);
        }
    }
    {
        float2 w = make_float2(tw.s64.x, -tw.s64.y);
        float2 b = cmul(r1, w);
        float2 a = r0;
        r0 = make_float2(a.x + b.x, a.y + b.y);
        r1 = make_float2(a.x - b.x, a.y - b.y);
    }
}

__global__ void hist_kernel(const float* __restrict__ pts, int* __restrict__ counts, int N){
    int i = blockIdx.x * blockDim.x + threadIdx.x;
    if (i >= N) return;
    float prx = pts[3*i] * RES, pry = pts[3*i+1] * RES;
    int lx = ((int)floorf(prx)) & 127, ly = ((int)floorf(pry)) & 127;
    atomicAdd(&counts[(lx << 7) | ly], 1);
}

__global__ __launch_bounds__(1024) void rowscan(const int* __restrict__ counts,
                                                int* __restrict__ starts,
                                                int* __restrict__ cursors){
    __shared__ int buf[2][1024];
    int t = threadIdx.x;
    int c[16];
    int base = t * 16;
    int s = 0;
    #pragma unroll
    for (int k = 0; k < 16; k++){ c[k] = counts[base + k]; s += c[k]; }
    buf[0][t] = s;
    __syncthreads();
    int cur = 0;
    for (int d = 1; d < 1024; d <<= 1){
        int v = buf[cur][t];
        if (t >= d) v += buf[cur][t - d];
        buf[cur ^ 1][t] = v;
        cur ^= 1;
        __syncthreads();
    }
    int incl = buf[cur][t];
    int run = incl - s;
    #pragma unroll
    for (int k = 0; k < 16; k++){ starts[base + k] = run; cursors[base + k] = run; run += c[k]; }
    if (t == 1023) starts[NROWS] = incl;
}

__global__ void scatter_sorted(const float* __restrict__ pts, const float* __restrict__ nrm,
                               int* __restrict__ cursors, float4* __restrict__ sorted4, int N){
    int i = blockIdx.x * blockDim.x + threadIdx.x;
    if (i >= N) return;
    float px = pts[3*i], py = pts[3*i+1], pz = pts[3*i+2];
    int lx = ((int)floorf(px * RES)) & 127, ly = ((int)floorf(py * RES)) & 127;
    int pos = atomicAdd(&cursors[(lx << 7) | ly], 1);
    sorted4[2*pos]     = make_float4(px, py, pz, nrm[3*i]);
    sorted4[2*pos + 1] = make_float4(nrm[3*i+1], nrm[3*i+2], 0.f, 0.f);
}

// ---- rasterize 32-wide y-strip, z-DIF per column, write HALF z-spectrum
// (natural kz 0..63) as one coalesced float4 per active lane.
// zF layout: [c][x][y][kz], index = ((c*128 + x)*128 + y)*KZ + kz (float2)
__global__ __launch_bounds__(768) void gather_z(const float4* __restrict__ sorted4,
                                                const int* __restrict__ starts,
                                                float2* __restrict__ zF){
    __shared__ float col[3][STRIPW][RES];   // 48 KB
    int x  = blockIdx.x >> 2;
    int y0 = (blockIdx.x & 3) << 5;
    int t = threadIdx.x;
    #pragma unroll
    for (int k = 0; k < 16; k++) ((float*)col)[t + 768*k] = 0.f;
    __syncthreads();
    int xm = (x + 127) & 127;
    int ybase = (y0 == 0) ? 127 : (y0 - 1);
    int n1 = (y0 == 0) ? 1 : 33;
    int n2 = 33 - n1;
    int a_s[4], a_e[4];
    { int r = (xm << 7) | ybase; a_s[0] = starts[r]; a_e[0] = starts[r + n1]; }
    { int r = (xm << 7);         a_s[1] = starts[r]; a_e[1] = starts[r + n2]; }
    { int r = (x  << 7) | ybase; a_s[2] = starts[r]; a_e[2] = starts[r + n1]; }
    { int r = (x  << 7);         a_s[3] = starts[r]; a_e[3] = starts[r + n2]; }
    int p1 = a_e[0] - a_s[0];
    int p2 = p1 + (a_e[1] - a_s[1]);
    int p3 = p2 + (a_e[2] - a_s[2]);
    int tot = p3 + (a_e[3] - a_s[3]);
    for (int base = 0; base < tot; base += 768){
        int k = base + t;
        if (k < tot){
            int i;
            if      (k < p1) i = a_s[0] + k;
            else if (k < p2) i = a_s[1] + (k - p1);
            else if (k < p3) i = a_s[2] + (k - p2);
            else             i = a_s[3] + (k - p3);
            float4 qa = sorted4[2*i];
            float4 qb = sorted4[2*i + 1];
            float prx = qa.x*RES, pry = qa.y*RES, prz = qa.z*RES;
            float flx = floorf(prx), fly = floorf(pry), flz = floorf(prz);
            float fx = prx - flx, fy = pry - fly, fz = prz - flz;
            int lxp = ((int)flx) & 127, lyp = ((int)fly) & 127, lz = ((int)flz) & 127;
            float wx = (lxp == x) ? (1.f - fx) : fx;
            int z1 = (lz + 1) & 127;
            float n0 = qa.w, nv1 = qb.x, nv2 = qb.y;
            int jA = (lyp - y0) & 127;
            int jB = (jA + 1) & 127;
            if (jA < STRIPW){
                float wy = wx * (1.f - fy);
                float w0 = wy * (1.f - fz), w1 = wy * fz;
                atomicAdd(&col[0][jA][lz], w0*n0);  atomicAdd(&col[0][jA][z1], w1*n0);
                atomicAdd(&col[1][jA][lz], w0*nv1); atomicAdd(&col[1][jA][z1], w1*nv1);
                atomicAdd(&col[2][jA][lz], w0*nv2); atomicAdd(&col[2][jA][z1], w1*nv2);
            }
            if (jB < STRIPW){
                float wy = wx * fy;
                float w0 = wy * (1.f - fz), w1 = wy * fz;
                atomicAdd(&col[0][jB][lz], w0*n0);  atomicAdd(&col[0][jB][z1], w1*n0);
                atomicAdd(&col[1][jB][lz], w0*nv1); atomicAdd(&col[1][jB][z1], w1*nv1);
                atomicAdd(&col[2][jB][lz], w0*nv2); atomicAdd(&col[2][jB][z1], w1*nv2);
            }
        }
    }
    __syncthreads();
    int w = t >> 6, tt = t & 63;
    TW tw = make_tw(tt);
    int k0 = brev7(tt);                 // even; brev7(tt+64) == k0+1
    #pragma unroll
    for (int r = 0; r < 8; r++){
        int idx = r * 12 + w;           // 0..95
        int c = idx >> 5, j = idx & 31;
        float2 r0 = make_float2(col[c][j][tt], 0.f);
        float2 r1 = make_float2(col[c][j][tt + 64], 0.f);
        dif128_t(r0, r1, tt, tw);
        if (k0 < KZ){
            size_t line = ((size_t)c * 16384 + ((size_t)x << 7) + (y0 + j));
            ((float4*)(zF + line * KZ))[k0 >> 1] = make_float4(r0.x, r0.y, r1.x, r1.y);
        }
    }
}

// ---- all-channel y pass over half-z: bufA = f_y*Y(V1) + f_z*Y(V2); bufB = Y(V0)
// buf layout: [x][y][kz], index = ((x<<7)|y)*KZ + kz
__global__ __launch_bounds__(1024) void mega_y(const float2* __restrict__ zF,
                                               float2* __restrict__ bufA,
                                               float2* __restrict__ bufB){
    __shared__ float2 tile[16][130];
    const size_t PL = (size_t)16384 * KZ;   // channel plane, float2
    int t = threadIdx.x;
    int x = blockIdx.x >> 2, z0 = (blockIdx.x & 3) << 4;
    int yv = t >> 3;
    int z2 = (t & 7) << 1;
    size_t gi = (((size_t)x << 7) + yv) * KZ + z0 + z2;   // even float2 index
    const float4* zF4 = (const float4*)zF;
    float4 L1 = zF4[(PL + gi) >> 1];
    float4 L2 = zF4[(2*PL + gi) >> 1];
    float4 L0 = zF4[gi >> 1];
    int w = t >> 6, tt = t & 63;
    TW tw = make_tw(tt);
    // c1: * f_y
    tile[z2][yv] = make_float2(L1.x, L1.y); tile[z2+1][yv] = make_float2(L1.z, L1.w);
    __syncthreads();
    float2 A0 = tile[w][tt], A1 = tile[w][tt + 64];
    __syncthreads();
    dif128_t(A0, A1, tt, tw);
    { float f0 = freq_of(tt), f1 = freq_of(tt + 64);
      A0.x *= f0; A0.y *= f0; A1.x *= f1; A1.y *= f1; }
    // c2: * f_z (natural kz!), accumulate
    tile[z2][yv] = make_float2(L2.x, L2.y); tile[z2+1][yv] = make_float2(L2.z, L2.w);
    __syncthreads();
    float2 C0 = tile[w][tt], C1 = tile[w][tt + 64];
    __syncthreads();
    dif128_t(C0, C1, tt, tw);
    { float fz = (float)(z0 + w);
      A0.x += fz*C0.x; A0.y += fz*C0.y; A1.x += fz*C1.x; A1.y += fz*C1.y; }
    // c0: plain
    tile[z2][yv] = make_float2(L0.x, L0.y); tile[z2+1][yv] = make_float2(L0.z, L0.w);
    __syncthreads();
    float2 B0 = tile[w][tt], B1 = tile[w][tt + 64];
    __syncthreads();
    dif128_t(B0, B1, tt, tw);
    tile[w][tt] = A0; tile[w][tt + 64] = A1;
    __syncthreads();
    { float2 a = tile[z2][yv], b = tile[z2+1][yv];
      ((float4*)bufA)[gi >> 1] = make_float4(a.x, a.y, b.x, b.y); }
    __syncthreads();
    tile[w][tt] = B0; tile[w][tt + 64] = B1;
    __syncthreads();
    { float2 a = tile[z2][yv], b = tile[z2+1][yv];
      ((float4*)bufB)[gi >> 1] = make_float4(a.x, a.y, b.x, b.y); }
}

// ---- x mega-pass over half-z ----
__global__ __launch_bounds__(1024) void x_mega(const float2* __restrict__ bufB,
                                               float2* __restrict__ bufA){
    __shared__ float2 tA[16][130];
    __shared__ float2 tB[16][130];
    int t = threadIdx.x;
    int y = blockIdx.x >> 2, z0 = (blockIdx.x & 3) << 4;
    int xv = t >> 3, z2 = (t & 7) << 1;
    size_t gi = (((size_t)xv << 7) + y) * KZ + z0 + z2;
    float4 LA = ((const float4*)bufA)[gi >> 1];
    float4 LB = ((const float4*)bufB)[gi >> 1];
    tA[z2][xv] = make_float2(LA.x, LA.y); tA[z2+1][xv] = make_float2(LA.z, LA.w);
    tB[z2][xv] = make_float2(LB.x, LB.y); tB[z2+1][xv] = make_float2(LB.z, LB.w);
    __syncthreads();
    int w = t >> 6, tt = t & 63;
    TW tw = make_tw(tt);
    float2 a0 = tA[w][tt], a1 = tA[w][tt + 64];
    float2 b0 = tB[w][tt], b1 = tB[w][tt + 64];
    dif128_t(a0, a1, tt, tw);
    dif128_t(b0, b1, tt, tw);
    float fy = freq_of(y), fz = (float)(z0 + w);
    float fyz = fy*fy + fz*fz;
    const float K = -2.f * (2.f/128.f) * (2.f/128.f);
    {
        float fx = freq_of(tt);
        float vx = a0.x + fx*b0.x, vy = a0.y + fx*b0.y;
        float usq = fx*fx + fyz;
        float s = __expf(K*usq) / ((usq + 1e-6f) * (2.f*(float)M_PI));
        a0 = make_float2(s*vy, -s*vx);
    }
    {
        float fx = freq_of(tt + 64);
        float vx = a1.x + fx*b1.x, vy = a1.y + fx*b1.y;
        float usq = fx*fx + fyz;
        float s = __expf(K*usq) / ((usq + 1e-6f) * (2.f*(float)M_PI));
        a1 = make_float2(s*vy, -s*vx);
    }
    dit128_t(a0, a1, tt, tw);
    tA[w][tt] = a0; tA[w][tt + 64] = a1;
    __syncthreads();
    { float2 a = tA[z2][xv], b = tA[z2+1][xv];
      ((float4*)bufA)[gi >> 1] = make_float4(a.x, a.y, b.x, b.y); }
}

// ---- inverse y pass over half-z ----
__global__ __launch_bounds__(1024) void inv_y(float2* __restrict__ data){
    __shared__ float2 tile[16][130];
    int t = threadIdx.x;
    int x = blockIdx.x >> 2, z0 = (blockIdx.x & 3) << 4;
    int yv = t >> 3, z2 = (t & 7) << 1;
    size_t gi = (((size_t)x << 7) + yv) * KZ + z0 + z2;
    float4 L = ((const float4*)data)[gi >> 1];
    tile[z2][yv] = make_float2(L.x, L.y); tile[z2+1][yv] = make_float2(L.z, L.w);
    __syncthreads();
    int w = t >> 6, tt = t & 63;
    TW tw = make_tw(tt);
    float2 r0 = tile[w][tt], r1 = tile[w][tt + 64];
    dit128_t(r0, r1, tt, tw);
    tile[w][tt] = r0; tile[w][tt + 64] = r1;
    __syncthreads();
    { float2 a = tile[z2][yv], b = tile[z2+1][yv];
      ((float4*)data)[gi >> 1] = make_float4(a.x, a.y, b.x, b.y); }
}

// ---- inverse z, Hermitian reconstruct from half-spectrum (natural kz 0..63) ----
__global__ __launch_bounds__(256) void inv_z_c2r(const float2* __restrict__ in, float* __restrict__ out){
    __shared__ float2 ld[4 * KZ];
    int t = threadIdx.x;
    int wid = t >> 6, tt = t & 63;
    size_t blk = (size_t)blockIdx.x;
    ld[t] = in[blk * (4*KZ) + t];      // 4 lines x 64, coalesced
    __syncthreads();
    const float2* D = ld + wid * KZ;
    int k0 = brev7(tt);                // even, 0..126
    int k1 = k0 + 1;                   // odd, 1..127
    float2 r0, r1;
    if (k0 < KZ)        r0 = D[k0];
    else if (k0 == 64)  r0 = make_float2(0.f, 0.f);       // dropped Nyquist
    else                { float2 v = D[128 - k0]; r0 = make_float2(v.x, -v.y); }
    if (k1 < KZ)        r1 = D[k1];
    else                { float2 v = D[128 - k1]; r1 = make_float2(v.x, -v.y); }
    TW tw = make_tw(tt);
    dit128_t(r0, r1, tt, tw);
    const float sc = 1.f / (float)RES3;
    float* q = out + (blk * 4 + wid) * RES;
    q[tt] = r0.x * sc; q[tt + 64] = r1.x * sc;
}

__global__ void interp_sum(const float* __restrict__ chi, const float* __restrict__ pts,
                           float* __restrict__ sum, int N){
    int i = blockIdx.x * blockDim.x + threadIdx.x;
    float val = 0.f;
    if (i < N){
        float px = pts[3*i], py = pts[3*i+1], pz = pts[3*i+2];
        float prx = px * RES, pry = py * RES, prz = pz * RES;
        float lox = floorf(prx), loy = floorf(pry), loz = floorf(prz);
        int lix = ((int)lox) & 127, liy = ((int)loy) & 127, liz = ((int)loz) & 127;
        int uix = ((int)ceilf(prx)) & 127, uiy = ((int)ceilf(pry)) & 127, uiz = ((int)ceilf(prz)) & 127;
        float fx = prx - lox, fy = pry - loy, fz = prz - loz;
        #pragma unroll
        for (int cx = 0; cx < 2; cx++){
            int ix = cx ? uix : lix;
            float wx = cx ? fx : 1.f - fx;
            #pragma unroll
            for (int cy = 0; cy < 2; cy++){
                int iy = cy ? uiy : liy;
                float wxy = wx * (cy ? fy : 1.f - fy);
                #pragma unroll
                for (int cz = 0; cz < 2; cz++){
                    int iz = cz ? uiz : liz;
                    float w = wxy * (cz ? fz : 1.f - fz);
                    val += w * chi[(ix << 14) + (iy << 7) + iz];
                }
            }
        }
    }
    __shared__ float red[256];
    int tid = threadIdx.x;
    red[tid] = val;
    __syncthreads();
    #pragma unroll
    for (int s2 = 128; s2 > 0; s2 >>= 1){
        if (tid < s2) red[tid] += red[tid + s2];
        __syncthreads();
    }
    if (tid == 0) atomicAdd(sum, red[0]);
}

__global__ void final_scale(const float* __restrict__ chi, const float* __restrict__ sum,
                            float* __restrict__ out, float invN){
    int i = blockIdx.x * blockDim.x + threadIdx.x;
    if (i >= RES3) return;
    float mean = sum[0] * invN;
    float sc = 0.5f / fabsf(chi[0] - mean);
    out[i] = sc * (chi[i] - mean);
}

extern "C" void kernel_launch(void* const* d_in, const int* in_sizes, int n_in,
                              void* d_out, int out_size, void* d_ws, size_t ws_size,
                              hipStream_t stream) {
    const float* points  = (const float*)d_in[0];
    const float* normals = (const float*)d_in[1];
    float* out = (float*)d_out;
    char* ws = (char*)d_ws;

    size_t off = 0;
    float2* zF     = (float2*)(ws + off); off += (size_t)3*RES2*KZ*8;   // 25.2 MB
    float2* bufA   = (float2*)(ws + off); off += (size_t)RES2*KZ*8;     //  8.4 MB
    float2* bufB   = (float2*)(ws + off); off += (size_t)RES2*KZ*8;     //  8.4 MB
    float*  chiP   = (float*) (ws + off); off += (size_t)RES3*4;        //  8.4 MB
    float*  sumb   = (float*) (ws + off); off += 64;
    int*    counts = (int*)   (ws + off); off += (size_t)NROWS*4;
    int*    starts = (int*)   (ws + off); off += (size_t)(NROWS+1)*4;
    int*    cursors= (int*)   (ws + off); off += (size_t)NROWS*4;
    off = (off + 15) & ~(size_t)15;
    float4* sorted4 = (float4*)(ws + off);                              // N*32 B

    int N = in_sizes[0] / 3;

    hipMemsetAsync(counts, 0, (size_t)NROWS*4, stream);
    hipMemsetAsync(sumb, 0, 16, stream);

    hist_kernel<<<(N + 255)/256, 256, 0, stream>>>(points, counts, N);
    rowscan<<<1, 1024, 0, stream>>>(counts, starts, cursors);
    scatter_sorted<<<(N + 255)/256, 256, 0, stream>>>(points, normals, cursors, sorted4, N);
    gather_z<<<128*4, 768, 0, stream>>>(sorted4, starts, zF);

    mega_y<<<512, 1024, 0, stream>>>(zF, bufA, bufB);
    x_mega<<<512, 1024, 0, stream>>>(bufB, bufA);
    inv_y<<<512, 1024, 0, stream>>>(bufA);
    inv_z_c2r<<<RES2/4, 256, 0, stream>>>(bufA, chiP);

    interp_sum<<<(N + 255)/256, 256, 0, stream>>>(chiP, points, sumb, N);
    final_scale<<<RES3/256, 256, 0, stream>>>(chiP, sumb, out, 1.0f / (float)N);
}

// Round 14
// 207.217 us; speedup vs baseline: 1.1435x; 1.0318x over previous
//
#include <hip/hip_runtime.h>
#include <math.h>

#define RES 128
#define RES2 (RES*RES)
#define RES3 (RES*RES*RES)
#define KZ 64         // retained z-frequencies 0..63 (Hermitian half, Nyquist dropped)
#define NROWS 16384
#define STRIPW 16

__device__ __forceinline__ int brev7(unsigned x){ return (int)(__brev(x) >> 25); }
__device__ __forceinline__ float freq_of(int s){ int k = brev7((unsigned)s); return (float)(k < 64 ? k : k - 128); }
__device__ __forceinline__ float2 cmul(float2 a, float2 b){
    return make_float2(a.x*b.x - a.y*b.y, a.x*b.y + a.y*b.x);
}
__device__ __forceinline__ float2 twd(float ang){ float s, c; __sincosf(ang, &s, &c); return make_float2(c, s); }

struct TW { float2 s64; float2 w[6]; };
__device__ __forceinline__ TW make_tw(int tt){
    TW t;
    t.s64 = twd(-(float)M_PI * (float)tt * (1.f/64.f));
    #pragma unroll
    for (int i = 0; i < 6; i++){
        int h = 32 >> i;
        t.w[i] = twd(-(float)M_PI * (float)(tt & (h - 1)) / (float)h);
    }
    return t;
}

// Forward DIF radix-2, natural -> bit-rev storage.
__device__ __forceinline__ void dif128_t(float2& r0, float2& r1, int tt, const TW& tw){
    {
        float2 a = r0, b = r1;
        r0 = make_float2(a.x + b.x, a.y + b.y);
        float2 d = make_float2(a.x - b.x, a.y - b.y);
        r1 = cmul(d, tw.s64);
    }
    #pragma unroll
    for (int i = 0; i < 6; i++){
        int h = 32 >> i;
        int bit = tt & h;
        float2 w = tw.w[i];
        float2 o0 = make_float2(__shfl_xor(r0.x, h), __shfl_xor(r0.y, h));
        float2 o1 = make_float2(__shfl_xor(r1.x, h), __shfl_xor(r1.y, h));
        if (!bit){
            r0.x += o0.x; r0.y += o0.y;
            r1.x += o1.x; r1.y += o1.y;
        } else {
            r0 = cmul(make_float2(o0.x - r0.x, o0.y - r0.y), w);
            r1 = cmul(make_float2(o1.x - r1.x, o1.y - r1.y), w);
        }
    }
}

// Inverse DIT radix-2, bit-rev -> natural (unscaled).
__device__ __forceinline__ void dit128_t(float2& r0, float2& r1, int tt, const TW& tw){
    #pragma unroll
    for (int i = 5; i >= 0; i--){
        int h = 32 >> i;
        int bit = tt & h;
        float2 w = make_float2(tw.w[i].x, -tw.w[i].y);
        float2 o0 = make_float2(__shfl_xor(r0.x, h), __shfl_xor(r0.y, h));
        float2 o1 = make_float2(__shfl_xor(r1.x, h), __shfl_xor(r1.y, h));
        if (!bit){
            float2 t0 = cmul(o0, w), t1 = cmul(o1, w);
            r0.x += t0.x; r0.y += t0.y;
            r1.x += t1.x; r1.y += t1.y;
        } else {
            float2 t0 = cmul(r0, w), t1 = cmul(r1, w);
            r0 = make_float2(o0.x - t0.x, o0.y - t0.y);
            r1 = make_float2(o1.x - t1.x, o1.y - t1.y);
        }
    }
    {
        float2 w = make_float2(tw.s64.x, -tw.s64.y);
        float2 b = cmul(r1, w);
        float2 a = r0;
        r0 = make_float2(a.x + b.x, a.y + b.y);
        r1 = make_float2(a.x - b.x, a.y - b.y);
    }
}

__global__ void hist_kernel(const float* __restrict__ pts, int* __restrict__ counts, int N){
    int i = blockIdx.x * blockDim.x + threadIdx.x;
    if (i >= N) return;
    float prx = pts[3*i] * RES, pry = pts[3*i+1] * RES;
    int lx = ((int)floorf(prx)) & 127, ly = ((int)floorf(pry)) & 127;
    atomicAdd(&counts[(lx << 7) | ly], 1);
}

__global__ __launch_bounds__(1024) void rowscan(const int* __restrict__ counts,
                                                int* __restrict__ starts,
                                                int* __restrict__ cursors){
    __shared__ int buf[2][1024];
    int t = threadIdx.x;
    int c[16];
    int base = t * 16;
    int s = 0;
    #pragma unroll
    for (int k = 0; k < 16; k++){ c[k] = counts[base + k]; s += c[k]; }
    buf[0][t] = s;
    __syncthreads();
    int cur = 0;
    for (int d = 1; d < 1024; d <<= 1){
        int v = buf[cur][t];
        if (t >= d) v += buf[cur][t - d];
        buf[cur ^ 1][t] = v;
        cur ^= 1;
        __syncthreads();
    }
    int incl = buf[cur][t];
    int run = incl - s;
    #pragma unroll
    for (int k = 0; k < 16; k++){ starts[base + k] = run; cursors[base + k] = run; run += c[k]; }
    if (t == 1023) starts[NROWS] = incl;
}

__global__ void scatter_sorted(const float* __restrict__ pts, const float* __restrict__ nrm,
                               int* __restrict__ cursors, float4* __restrict__ sorted4, int N){
    int i = blockIdx.x * blockDim.x + threadIdx.x;
    if (i >= N) return;
    float px = pts[3*i], py = pts[3*i+1], pz = pts[3*i+2];
    int lx = ((int)floorf(px * RES)) & 127, ly = ((int)floorf(py * RES)) & 127;
    int pos = atomicAdd(&cursors[(lx << 7) | ly], 1);
    sorted4[2*pos]     = make_float4(px, py, pz, nrm[3*i]);
    sorted4[2*pos + 1] = make_float4(nrm[3*i+1], nrm[3*i+2], 0.f, 0.f);
}

// ---- rasterize 16-wide y-strip, z-DIF per column, write HALF z-spectrum.
// 512 threads = 8 waves; 1024 blocks = 4 blocks/CU (full wave occupancy).
// zF layout: [c][x][y][kz], index = ((c*128 + x)*128 + y)*KZ + kz (float2)
__global__ __launch_bounds__(512) void gather_z(const float4* __restrict__ sorted4,
                                                const int* __restrict__ starts,
                                                float2* __restrict__ zF){
    __shared__ float col[3][STRIPW][RES];   // 24 KB
    int x  = blockIdx.x >> 3;          // 0..127
    int y0 = (blockIdx.x & 7) << 4;    // 0,16,...,112
    int t = threadIdx.x;
    #pragma unroll
    for (int k = 0; k < 12; k++) ((float*)col)[t + 512*k] = 0.f;   // 6144 floats
    __syncthreads();
    int xm = (x + 127) & 127;
    // rows needed: ly in {y0-1 .. y0+15} (17 consecutive, split at wrap when y0==0)
    int ybase = (y0 == 0) ? 127 : (y0 - 1);
    int n1 = (y0 == 0) ? 1 : 17;
    int n2 = 17 - n1;
    int a_s[4], a_e[4];
    { int r = (xm << 7) | ybase; a_s[0] = starts[r]; a_e[0] = starts[r + n1]; }
    { int r = (xm << 7);         a_s[1] = starts[r]; a_e[1] = starts[r + n2]; }
    { int r = (x  << 7) | ybase; a_s[2] = starts[r]; a_e[2] = starts[r + n1]; }
    { int r = (x  << 7);         a_s[3] = starts[r]; a_e[3] = starts[r + n2]; }
    int p1 = a_e[0] - a_s[0];
    int p2 = p1 + (a_e[1] - a_s[1]);
    int p3 = p2 + (a_e[2] - a_s[2]);
    int tot = p3 + (a_e[3] - a_s[3]);
    for (int base = 0; base < tot; base += 512){
        int k = base + t;
        if (k < tot){
            int i;
            if      (k < p1) i = a_s[0] + k;
            else if (k < p2) i = a_s[1] + (k - p1);
            else if (k < p3) i = a_s[2] + (k - p2);
            else             i = a_s[3] + (k - p3);
            float4 qa = sorted4[2*i];
            float4 qb = sorted4[2*i + 1];
            float prx = qa.x*RES, pry = qa.y*RES, prz = qa.z*RES;
            float flx = floorf(prx), fly = floorf(pry), flz = floorf(prz);
            float fx = prx - flx, fy = pry - fly, fz = prz - flz;
            int lxp = ((int)flx) & 127, lyp = ((int)fly) & 127, lz = ((int)flz) & 127;
            float wx = (lxp == x) ? (1.f - fx) : fx;
            int z1 = (lz + 1) & 127;
            float n0 = qa.w, nv1 = qb.x, nv2 = qb.y;
            int jA = (lyp - y0) & 127;
            int jB = (jA + 1) & 127;
            if (jA < STRIPW){
                float wy = wx * (1.f - fy);
                float w0 = wy * (1.f - fz), w1 = wy * fz;
                atomicAdd(&col[0][jA][lz], w0*n0);  atomicAdd(&col[0][jA][z1], w1*n0);
                atomicAdd(&col[1][jA][lz], w0*nv1); atomicAdd(&col[1][jA][z1], w1*nv1);
                atomicAdd(&col[2][jA][lz], w0*nv2); atomicAdd(&col[2][jA][z1], w1*nv2);
            }
            if (jB < STRIPW){
                float wy = wx * fy;
                float w0 = wy * (1.f - fz), w1 = wy * fz;
                atomicAdd(&col[0][jB][lz], w0*n0);  atomicAdd(&col[0][jB][z1], w1*n0);
                atomicAdd(&col[1][jB][lz], w0*nv1); atomicAdd(&col[1][jB][z1], w1*nv1);
                atomicAdd(&col[2][jB][lz], w0*nv2); atomicAdd(&col[2][jB][z1], w1*nv2);
            }
        }
    }
    __syncthreads();
    int w = t >> 6, tt = t & 63;       // 8 waves
    TW tw = make_tw(tt);
    int k0 = brev7(tt);                 // even; brev7(tt+64) == k0+1
    #pragma unroll
    for (int r = 0; r < 6; r++){
        int idx = r * 8 + w;            // 0..47
        int c = idx >> 4, j = idx & 15;
        float2 r0 = make_float2(col[c][j][tt], 0.f);
        float2 r1 = make_float2(col[c][j][tt + 64], 0.f);
        dif128_t(r0, r1, tt, tw);
        if (k0 < KZ){
            size_t line = ((size_t)c * 16384 + ((size_t)x << 7) + (y0 + j));
            ((float4*)(zF + line * KZ))[k0 >> 1] = make_float4(r0.x, r0.y, r1.x, r1.y);
        }
    }
}

// ---- all-channel y pass over half-z: bufA = f_y*Y(V1) + f_z*Y(V2); bufB = Y(V0)
// buf layout: [x][y][kz], index = ((x<<7)|y)*KZ + kz
__global__ __launch_bounds__(1024) void mega_y(const float2* __restrict__ zF,
                                               float2* __restrict__ bufA,
                                               float2* __restrict__ bufB){
    __shared__ float2 tile[16][130];
    const size_t PL = (size_t)16384 * KZ;   // channel plane, float2
    int t = threadIdx.x;
    int x = blockIdx.x >> 2, z0 = (blockIdx.x & 3) << 4;
    int yv = t >> 3;
    int z2 = (t & 7) << 1;
    size_t gi = (((size_t)x << 7) + yv) * KZ + z0 + z2;   // even float2 index
    const float4* zF4 = (const float4*)zF;
    float4 L1 = zF4[(PL + gi) >> 1];
    float4 L2 = zF4[(2*PL + gi) >> 1];
    float4 L0 = zF4[gi >> 1];
    int w = t >> 6, tt = t & 63;
    TW tw = make_tw(tt);
    // c1: * f_y
    tile[z2][yv] = make_float2(L1.x, L1.y); tile[z2+1][yv] = make_float2(L1.z, L1.w);
    __syncthreads();
    float2 A0 = tile[w][tt], A1 = tile[w][tt + 64];
    __syncthreads();
    dif128_t(A0, A1, tt, tw);
    { float f0 = freq_of(tt), f1 = freq_of(tt + 64);
      A0.x *= f0; A0.y *= f0; A1.x *= f1; A1.y *= f1; }
    // c2: * f_z (natural kz), accumulate
    tile[z2][yv] = make_float2(L2.x, L2.y); tile[z2+1][yv] = make_float2(L2.z, L2.w);
    __syncthreads();
    float2 C0 = tile[w][tt], C1 = tile[w][tt + 64];
    __syncthreads();
    dif128_t(C0, C1, tt, tw);
    { float fz = (float)(z0 + w);
      A0.x += fz*C0.x; A0.y += fz*C0.y; A1.x += fz*C1.x; A1.y += fz*C1.y; }
    // c0: plain
    tile[z2][yv] = make_float2(L0.x, L0.y); tile[z2+1][yv] = make_float2(L0.z, L0.w);
    __syncthreads();
    float2 B0 = tile[w][tt], B1 = tile[w][tt + 64];
    __syncthreads();
    dif128_t(B0, B1, tt, tw);
    tile[w][tt] = A0; tile[w][tt + 64] = A1;
    __syncthreads();
    { float2 a = tile[z2][yv], b = tile[z2+1][yv];
      ((float4*)bufA)[gi >> 1] = make_float4(a.x, a.y, b.x, b.y); }
    __syncthreads();
    tile[w][tt] = B0; tile[w][tt + 64] = B1;
    __syncthreads();
    { float2 a = tile[z2][yv], b = tile[z2+1][yv];
      ((float4*)bufB)[gi >> 1] = make_float4(a.x, a.y, b.x, b.y); }
}

// ---- x mega-pass over half-z ----
__global__ __launch_bounds__(1024) void x_mega(const float2* __restrict__ bufB,
                                               float2* __restrict__ bufA){
    __shared__ float2 tA[16][130];
    __shared__ float2 tB[16][130];
    int t = threadIdx.x;
    int y = blockIdx.x >> 2, z0 = (blockIdx.x & 3) << 4;
    int xv = t >> 3, z2 = (t & 7) << 1;
    size_t gi = (((size_t)xv << 7) + y) * KZ + z0 + z2;
    float4 LA = ((const float4*)bufA)[gi >> 1];
    float4 LB = ((const float4*)bufB)[gi >> 1];
    tA[z2][xv] = make_float2(LA.x, LA.y); tA[z2+1][xv] = make_float2(LA.z, LA.w);
    tB[z2][xv] = make_float2(LB.x, LB.y); tB[z2+1][xv] = make_float2(LB.z, LB.w);
    __syncthreads();
    int w = t >> 6, tt = t & 63;
    TW tw = make_tw(tt);
    float2 a0 = tA[w][tt], a1 = tA[w][tt + 64];
    float2 b0 = tB[w][tt], b1 = tB[w][tt + 64];
    dif128_t(a0, a1, tt, tw);
    dif128_t(b0, b1, tt, tw);
    float fy = freq_of(y), fz = (float)(z0 + w);
    float fyz = fy*fy + fz*fz;
    const float K = -2.f * (2.f/128.f) * (2.f/128.f);
    {
        float fx = freq_of(tt);
        float vx = a0.x + fx*b0.x, vy = a0.y + fx*b0.y;
        float usq = fx*fx + fyz;
        float s = __expf(K*usq) / ((usq + 1e-6f) * (2.f*(float)M_PI));
        a0 = make_float2(s*vy, -s*vx);
    }
    {
        float fx = freq_of(tt + 64);
        float vx = a1.x + fx*b1.x, vy = a1.y + fx*b1.y;
        float usq = fx*fx + fyz;
        float s = __expf(K*usq) / ((usq + 1e-6f) * (2.f*(float)M_PI));
        a1 = make_float2(s*vy, -s*vx);
    }
    dit128_t(a0, a1, tt, tw);
    tA[w][tt] = a0; tA[w][tt + 64] = a1;
    __syncthreads();
    { float2 a = tA[z2][xv], b = tA[z2+1][xv];
      ((float4*)bufA)[gi >> 1] = make_float4(a.x, a.y, b.x, b.y); }
}

// ---- inverse y pass over half-z ----
__global__ __launch_bounds__(1024) void inv_y(float2* __restrict__ data){
    __shared__ float2 tile[16][130];
    int t = threadIdx.x;
    int x = blockIdx.x >> 2, z0 = (blockIdx.x & 3) << 4;
    int yv = t >> 3, z2 = (t & 7) << 1;
    size_t gi = (((size_t)x << 7) + yv) * KZ + z0 + z2;
    float4 L = ((const float4*)data)[gi >> 1];
    tile[z2][yv] = make_float2(L.x, L.y); tile[z2+1][yv] = make_float2(L.z, L.w);
    __syncthreads();
    int w = t >> 6, tt = t & 63;
    TW tw = make_tw(tt);
    float2 r0 = tile[w][tt], r1 = tile[w][tt + 64];
    dit128_t(r0, r1, tt, tw);
    tile[w][tt] = r0; tile[w][tt + 64] = r1;
    __syncthreads();
    { float2 a = tile[z2][yv], b = tile[z2+1][yv];
      ((float4*)data)[gi >> 1] = make_float4(a.x, a.y, b.x, b.y); }
}

// ---- inverse z, Hermitian reconstruct from half-spectrum (natural kz 0..63) ----
__global__ __launch_bounds__(256) void inv_z_c2r(const float2* __restrict__ in, float* __restrict__ out){
    __shared__ float2 ld[4 * KZ];
    int t = threadIdx.x;
    int wid = t >> 6, tt = t & 63;
    size_t blk = (size_t)blockIdx.x;
    ld[t] = in[blk * (4*KZ) + t];      // 4 lines x 64, coalesced
    __syncthreads();
    const float2* D = ld + wid * KZ;
    int k0 = brev7(tt);                // even, 0..126
    int k1 = k0 + 1;                   // odd, 1..127
    float2 r0, r1;
    if (k0 < KZ)        r0 = D[k0];
    else if (k0 == 64)  r0 = make_float2(0.f, 0.f);       // dropped Nyquist
    else                { float2 v = D[128 - k0]; r0 = make_float2(v.x, -v.y); }
    if (k1 < KZ)        r1 = D[k1];
    else                { float2 v = D[128 - k1]; r1 = make_float2(v.x, -v.y); }
    TW tw = make_tw(tt);
    dit128_t(r0, r1, tt, tw);
    const float sc = 1.f / (float)RES3;
    float* q = out + (blk * 4 + wid) * RES;
    q[tt] = r0.x * sc; q[tt + 64] = r1.x * sc;
}

// interp from the SORTED point array (coalesced float4 + sorted gather locality)
__global__ void interp_sum(const float* __restrict__ chi, const float4* __restrict__ sorted4,
                           float* __restrict__ sum, int N){
    int i = blockIdx.x * blockDim.x + threadIdx.x;
    float val = 0.f;
    if (i < N){
        float4 qa = sorted4[2*i];
        float prx = qa.x * RES, pry = qa.y * RES, prz = qa.z * RES;
        float lox = floorf(prx), loy = floorf(pry), loz = floorf(prz);
        int lix = ((int)lox) & 127, liy = ((int)loy) & 127, liz = ((int)loz) & 127;
        int uix = ((int)ceilf(prx)) & 127, uiy = ((int)ceilf(pry)) & 127, uiz = ((int)ceilf(prz)) & 127;
        float fx = prx - lox, fy = pry - loy, fz = prz - loz;
        #pragma unroll
        for (int cx = 0; cx < 2; cx++){
            int ix = cx ? uix : lix;
            float wx = cx ? fx : 1.f - fx;
            #pragma unroll
            for (int cy = 0; cy < 2; cy++){
                int iy = cy ? uiy : liy;
                float wxy = wx * (cy ? fy : 1.f - fy);
                #pragma unroll
                for (int cz = 0; cz < 2; cz++){
                    int iz = cz ? uiz : liz;
                    float w = wxy * (cz ? fz : 1.f - fz);
                    val += w * chi[(ix << 14) + (iy << 7) + iz];
                }
            }
        }
    }
    __shared__ float red[256];
    int tid = threadIdx.x;
    red[tid] = val;
    __syncthreads();
    #pragma unroll
    for (int s2 = 128; s2 > 0; s2 >>= 1){
        if (tid < s2) red[tid] += red[tid + s2];
        __syncthreads();
    }
    if (tid == 0) atomicAdd(sum, red[0]);
}

__global__ void final_scale(const float4* __restrict__ chi4, const float* __restrict__ chi,
                            const float* __restrict__ sum, float4* __restrict__ out4, float invN){
    int i = blockIdx.x * blockDim.x + threadIdx.x;
    if (i >= RES3/4) return;
    float mean = sum[0] * invN;
    float sc = 0.5f / fabsf(chi[0] - mean);
    float4 v = chi4[i];
    out4[i] = make_float4(sc*(v.x - mean), sc*(v.y - mean), sc*(v.z - mean), sc*(v.w - mean));
}

extern "C" void kernel_launch(void* const* d_in, const int* in_sizes, int n_in,
                              void* d_out, int out_size, void* d_ws, size_t ws_size,
                              hipStream_t stream) {
    const float* points  = (const float*)d_in[0];
    const float* normals = (const float*)d_in[1];
    float* out = (float*)d_out;
    char* ws = (char*)d_ws;

    size_t off = 0;
    float2* zF     = (float2*)(ws + off); off += (size_t)3*RES2*KZ*8;   // 25.2 MB
    float2* bufA   = (float2*)(ws + off); off += (size_t)RES2*KZ*8;     //  8.4 MB
    float2* bufB   = (float2*)(ws + off); off += (size_t)RES2*KZ*8;     //  8.4 MB
    float*  chiP   = (float*) (ws + off); off += (size_t)RES3*4;        //  8.4 MB
    float*  sumb   = (float*) (ws + off); off += 64;
    int*    counts = (int*)   (ws + off); off += (size_t)NROWS*4;
    int*    starts = (int*)   (ws + off); off += (size_t)(NROWS+1)*4;
    int*    cursors= (int*)   (ws + off); off += (size_t)NROWS*4;
    off = (off + 15) & ~(size_t)15;
    float4* sorted4 = (float4*)(ws + off);                              // N*32 B

    int N = in_sizes[0] / 3;

    hipMemsetAsync(counts, 0, (size_t)NROWS*4, stream);
    hipMemsetAsync(sumb, 0, 16, stream);

    hist_kernel<<<(N + 255)/256, 256, 0, stream>>>(points, counts, N);
    rowscan<<<1, 1024, 0, stream>>>(counts, starts, cursors);
    scatter_sorted<<<(N + 255)/256, 256, 0, stream>>>(points, normals, cursors, sorted4, N);
    gather_z<<<128*8, 512, 0, stream>>>(sorted4, starts, zF);

    mega_y<<<512, 1024, 0, stream>>>(zF, bufA, bufB);
    x_mega<<<512, 1024, 0, stream>>>(bufB, bufA);
    inv_y<<<512, 1024, 0, stream>>>(bufA);
    inv_z_c2r<<<RES2/4, 256, 0, stream>>>(bufA, chiP);

    interp_sum<<<(N + 255)/256, 256, 0, stream>>>(chiP, sorted4, sumb, N);
    final_scale<<<RES3/1024, 256, 0, stream>>>((const float4*)chiP, chiP, sumb, (float4*)out, 1.0f / (float)N);
}